// Round 1
// baseline (5508.797 us; speedup 1.0000x reference)
//
#include <hip/hip_runtime.h>
#include <math.h>

#define NB 1024
#define NT 64
#define NH 512
#define NE 200000
#define LN_EPS 1e-5f

// ---------------- LayerNorm block statistics (256 threads, 512 elems) -------
__device__ __forceinline__ void ln_stats(float sum, float sq, float& mean, float& rstd) {
#pragma unroll
  for (int o = 32; o > 0; o >>= 1) {
    sum += __shfl_down(sum, o);
    sq  += __shfl_down(sq, o);
  }
  __shared__ float red[8];
  const int wid = threadIdx.x >> 6;
  if ((threadIdx.x & 63) == 0) { red[wid * 2] = sum; red[wid * 2 + 1] = sq; }
  __syncthreads();
  if (threadIdx.x == 0) {
    const float ts = red[0] + red[2] + red[4] + red[6];
    const float tq = red[1] + red[3] + red[5] + red[7];
    const float m  = ts * (1.0f / NH);
    const float var = tq * (1.0f / NH) - m * m;
    red[0] = m;
    red[1] = rsqrtf(var + LN_EPS);
  }
  __syncthreads();
  mean = red[0];
  rstd = red[1];
}

// ---------------- active mask: active[b][t], precomputed from actions -------
__global__ void active_kernel(const int* __restrict__ actions,
                              const int* __restrict__ stopidx,
                              int* __restrict__ act_mask) {
  const int b = blockIdx.x * blockDim.x + threadIdx.x;
  if (b >= NB) return;
  const int si = stopidx[b];
  bool done = false;
  for (int t = 0; t < NT; ++t) {
    const int a = actions[b * NT + t];
    const bool is_stop = (a == si) || (a < 0);
    act_mask[b * NT + t] = (!done && !is_stop) ? 1 : 0;
    done = done || is_stop;
  }
}

// ---------------- h0 = LN(question + segment_mean(node_tokens)) -------------
__global__ void h0_kernel(const float* __restrict__ q,
                          const float* __restrict__ nodes,
                          const int* __restrict__ locals,
                          const int* __restrict__ ptr,
                          const float* __restrict__ lnw,
                          const float* __restrict__ lnb,
                          float* __restrict__ h0) {
  const int b = blockIdx.x;
  const int i = threadIdx.x * 2;
  const int p0 = ptr[b], p1 = ptr[b + 1];
  const float denom = fmaxf((float)(p1 - p0), 1.0f);
  float s0 = 0.f, s1 = 0.f;
  for (int p = p0; p < p1; ++p) {
    const int node = locals[p];
    const float2 nv = *(const float2*)&nodes[(size_t)node * NH + i];
    s0 += nv.x; s1 += nv.y;
  }
  const float2 qv = *(const float2*)&q[(size_t)b * NH + i];
  const float v0 = qv.x + s0 / denom;
  const float v1 = qv.y + s1 / denom;
  float mean, rstd;
  ln_stats(v0 + v1, v0 * v0 + v1 * v1, mean, rstd);
  const float2 lw = *(const float2*)&lnw[i];
  const float2 lb = *(const float2*)&lnb[i];
  float2 o;
  o.x = (v0 - mean) * rstd * lw.x + lb.x;
  o.y = (v1 - mean) * rstd * lw.y + lb.y;
  *(float2*)&h0[(size_t)b * NH + i] = o;
}

// ---------------- emb_t = LN(h)  (emitted BEFORE the update) ----------------
__global__ void emb_kernel(const float* __restrict__ h,
                           const float* __restrict__ lnw,
                           const float* __restrict__ lnb,
                           float* __restrict__ out, int t) {
  const int b = blockIdx.x;
  const int i = threadIdx.x * 2;
  const float2 hv = *(const float2*)&h[(size_t)b * NH + i];
  float mean, rstd;
  ln_stats(hv.x + hv.y, hv.x * hv.x + hv.y * hv.y, mean, rstd);
  const float2 lw = *(const float2*)&lnw[i];
  const float2 lb = *(const float2*)&lnb[i];
  float2 o;
  o.x = (hv.x - mean) * rstd * lw.x + lb.x;
  o.y = (hv.y - mean) * rstd * lw.y + lb.y;
  *(float2*)&out[(size_t)b * NT * NH + (size_t)t * NH + i] = o;
}

// ---------------- fused GRU step: gates GEMM + nonlinearity + h update ------
#define BM 64
#define BN 32
#define BK 32

__device__ __forceinline__ float sigmoid_f(float x) {
  return 1.0f / (1.0f + __expf(-x));
}
__device__ __forceinline__ float tanh_f(float x) {
  x = fminf(fmaxf(x, -15.0f), 15.0f);
  const float e = __expf(2.0f * x);
  return (e - 1.0f) / (e + 1.0f);
}

__global__ __launch_bounds__(256) void gates_kernel(
    const float* __restrict__ hcur, float* __restrict__ hnext,
    const int* __restrict__ actions, const int* __restrict__ act_mask,
    const float* __restrict__ edge_tokens,
    const float* __restrict__ w_ih, const float* __restrict__ w_hh,
    const float* __restrict__ b_ih, const float* __restrict__ b_hh,
    int t) {
  __shared__ float As[BK][BM + 4];      // A stored transposed: As[k][m]
  __shared__ float Ws[3][BK][BN + 2];   // Ws[gate][k][n]
  __shared__ int s_any;

  const int tid = threadIdx.x;
  const int c0 = blockIdx.x * BN;  // hidden-col tile
  const int b0 = blockIdx.y * BM;  // batch-row tile

  if (tid == 0) s_any = 0;
  __syncthreads();
  if (tid < BM) {
    if (act_mask[(b0 + tid) * NT + t]) atomicOr(&s_any, 1);
  }
  __syncthreads();

  const int lk = tid & 7;    // k-float4 index (k = lk*4)
  const int lm = tid >> 3;   // 0..31 (A row / W n index)

  if (!s_any) {
    // whole tile inactive: h passes through
#pragma unroll
    for (int mm = 0; mm < BM; mm += 32) {
      const size_t off = (size_t)(b0 + lm + mm) * NH + c0 + lk * 4;
      *(float4*)&hnext[off] = *(const float4*)&hcur[off];
    }
    return;
  }

  float accR[4][2] = {{0}}, accZ[4][2] = {{0}}, accNI[4][2] = {{0}}, accNH[4][2] = {{0}};
  const int tx = tid & 15, ty = tid >> 4;
  const int tm = ty * 4;   // row offset within tile (4 rows)
  const int tn = tx * 2;   // col offset within tile (2 cols)

  int a0i = actions[(b0 + lm) * NT + t];
  int a1i = actions[(b0 + lm + 32) * NT + t];
  a0i = min(max(a0i, 0), NE - 1);
  a1i = min(max(a1i, 0), NE - 1);
  const float* __restrict__ Ab0 = &edge_tokens[(size_t)a0i * NH];
  const float* __restrict__ Ab1 = &edge_tokens[(size_t)a1i * NH];

  // ===== phase 0: A = x (gathered edge tokens), W = w_ih; n-part -> accNI ===
  for (int kb = 0; kb < NH; kb += BK) {
    const float4 av0 = *(const float4*)&Ab0[kb + lk * 4];
    const float4 av1 = *(const float4*)&Ab1[kb + lk * 4];
    const float4 wr = *(const float4*)&w_ih[(size_t)(c0 + lm) * NH + kb + lk * 4];
    const float4 wz = *(const float4*)&w_ih[(size_t)(NH + c0 + lm) * NH + kb + lk * 4];
    const float4 wn = *(const float4*)&w_ih[(size_t)(2 * NH + c0 + lm) * NH + kb + lk * 4];
    __syncthreads();
    As[lk * 4 + 0][lm] = av0.x; As[lk * 4 + 1][lm] = av0.y;
    As[lk * 4 + 2][lm] = av0.z; As[lk * 4 + 3][lm] = av0.w;
    As[lk * 4 + 0][lm + 32] = av1.x; As[lk * 4 + 1][lm + 32] = av1.y;
    As[lk * 4 + 2][lm + 32] = av1.z; As[lk * 4 + 3][lm + 32] = av1.w;
    Ws[0][lk * 4 + 0][lm] = wr.x; Ws[0][lk * 4 + 1][lm] = wr.y;
    Ws[0][lk * 4 + 2][lm] = wr.z; Ws[0][lk * 4 + 3][lm] = wr.w;
    Ws[1][lk * 4 + 0][lm] = wz.x; Ws[1][lk * 4 + 1][lm] = wz.y;
    Ws[1][lk * 4 + 2][lm] = wz.z; Ws[1][lk * 4 + 3][lm] = wz.w;
    Ws[2][lk * 4 + 0][lm] = wn.x; Ws[2][lk * 4 + 1][lm] = wn.y;
    Ws[2][lk * 4 + 2][lm] = wn.z; Ws[2][lk * 4 + 3][lm] = wn.w;
    __syncthreads();
#pragma unroll
    for (int k = 0; k < BK; ++k) {
      const float4 a = *(const float4*)&As[k][tm];
      const float2 vr = *(const float2*)&Ws[0][k][tn];
      const float2 vz = *(const float2*)&Ws[1][k][tn];
      const float2 vn = *(const float2*)&Ws[2][k][tn];
      const float am[4] = {a.x, a.y, a.z, a.w};
#pragma unroll
      for (int i = 0; i < 4; ++i) {
        accR[i][0] += am[i] * vr.x; accR[i][1] += am[i] * vr.y;
        accZ[i][0] += am[i] * vz.x; accZ[i][1] += am[i] * vz.y;
        accNI[i][0] += am[i] * vn.x; accNI[i][1] += am[i] * vn.y;
      }
    }
  }

  // ===== phase 1: A = h, W = w_hh; n-part -> accNH ==========================
  const float* __restrict__ Hb0 = &hcur[(size_t)(b0 + lm) * NH];
  const float* __restrict__ Hb1 = &hcur[(size_t)(b0 + lm + 32) * NH];
  for (int kb = 0; kb < NH; kb += BK) {
    const float4 av0 = *(const float4*)&Hb0[kb + lk * 4];
    const float4 av1 = *(const float4*)&Hb1[kb + lk * 4];
    const float4 wr = *(const float4*)&w_hh[(size_t)(c0 + lm) * NH + kb + lk * 4];
    const float4 wz = *(const float4*)&w_hh[(size_t)(NH + c0 + lm) * NH + kb + lk * 4];
    const float4 wn = *(const float4*)&w_hh[(size_t)(2 * NH + c0 + lm) * NH + kb + lk * 4];
    __syncthreads();
    As[lk * 4 + 0][lm] = av0.x; As[lk * 4 + 1][lm] = av0.y;
    As[lk * 4 + 2][lm] = av0.z; As[lk * 4 + 3][lm] = av0.w;
    As[lk * 4 + 0][lm + 32] = av1.x; As[lk * 4 + 1][lm + 32] = av1.y;
    As[lk * 4 + 2][lm + 32] = av1.z; As[lk * 4 + 3][lm + 32] = av1.w;
    Ws[0][lk * 4 + 0][lm] = wr.x; Ws[0][lk * 4 + 1][lm] = wr.y;
    Ws[0][lk * 4 + 2][lm] = wr.z; Ws[0][lk * 4 + 3][lm] = wr.w;
    Ws[1][lk * 4 + 0][lm] = wz.x; Ws[1][lk * 4 + 1][lm] = wz.y;
    Ws[1][lk * 4 + 2][lm] = wz.z; Ws[1][lk * 4 + 3][lm] = wz.w;
    Ws[2][lk * 4 + 0][lm] = wn.x; Ws[2][lk * 4 + 1][lm] = wn.y;
    Ws[2][lk * 4 + 2][lm] = wn.z; Ws[2][lk * 4 + 3][lm] = wn.w;
    __syncthreads();
#pragma unroll
    for (int k = 0; k < BK; ++k) {
      const float4 a = *(const float4*)&As[k][tm];
      const float2 vr = *(const float2*)&Ws[0][k][tn];
      const float2 vz = *(const float2*)&Ws[1][k][tn];
      const float2 vn = *(const float2*)&Ws[2][k][tn];
      const float am[4] = {a.x, a.y, a.z, a.w};
#pragma unroll
      for (int i = 0; i < 4; ++i) {
        accR[i][0] += am[i] * vr.x; accR[i][1] += am[i] * vr.y;
        accZ[i][0] += am[i] * vz.x; accZ[i][1] += am[i] * vz.y;
        accNH[i][0] += am[i] * vn.x; accNH[i][1] += am[i] * vn.y;
      }
    }
  }

  // ===== epilogue: gates + update ===========================================
  const int c = c0 + tn;
  const float bR0 = b_ih[c] + b_hh[c];
  const float bR1 = b_ih[c + 1] + b_hh[c + 1];
  const float bZ0 = b_ih[NH + c] + b_hh[NH + c];
  const float bZ1 = b_ih[NH + c + 1] + b_hh[NH + c + 1];
  const float bI0 = b_ih[2 * NH + c],     bI1 = b_ih[2 * NH + c + 1];
  const float bH0 = b_hh[2 * NH + c],     bH1 = b_hh[2 * NH + c + 1];
#pragma unroll
  for (int i = 0; i < 4; ++i) {
    const int m = b0 + tm + i;
    const int act = act_mask[m * NT + t];
    const float2 hp = *(const float2*)&hcur[(size_t)m * NH + c];
    const float r0 = sigmoid_f(accR[i][0] + bR0);
    const float r1 = sigmoid_f(accR[i][1] + bR1);
    const float z0 = sigmoid_f(accZ[i][0] + bZ0);
    const float z1 = sigmoid_f(accZ[i][1] + bZ1);
    const float nn0 = tanh_f(accNI[i][0] + bI0 + r0 * (accNH[i][0] + bH0));
    const float nn1 = tanh_f(accNI[i][1] + bI1 + r1 * (accNH[i][1] + bH1));
    float2 o;
    o.x = act ? ((1.0f - z0) * nn0 + z0 * hp.x) : hp.x;
    o.y = act ? ((1.0f - z1) * nn1 + z1 * hp.y) : hp.y;
    *(float2*)&hnext[(size_t)m * NH + c] = o;
  }
}

// ---------------- host-side launch ------------------------------------------
extern "C" void kernel_launch(void* const* d_in, const int* in_sizes, int n_in,
                              void* d_out, int out_size, void* d_ws, size_t ws_size,
                              hipStream_t stream) {
  const int*   actions      = (const int*)d_in[0];
  const float* edge_tokens  = (const float*)d_in[1];
  const int*   stop_indices = (const int*)d_in[2];
  const float* question     = (const float*)d_in[3];
  const float* node_tokens  = (const float*)d_in[4];
  const int*   start_locals = (const int*)d_in[5];
  const int*   start_ptr    = (const int*)d_in[6];
  const float* w_ih         = (const float*)d_in[7];
  const float* w_hh         = (const float*)d_in[8];
  const float* b_ih         = (const float*)d_in[9];
  const float* b_hh         = (const float*)d_in[10];
  const float* ln_w         = (const float*)d_in[11];
  const float* ln_b         = (const float*)d_in[12];
  float* out = (float*)d_out;

  float* hbuf0 = (float*)d_ws;
  float* hbuf1 = hbuf0 + (size_t)NB * NH;
  int* act_mask = (int*)(hbuf1 + (size_t)NB * NH);

  active_kernel<<<NB / 256, 256, 0, stream>>>(actions, stop_indices, act_mask);
  h0_kernel<<<NB, 256, 0, stream>>>(question, node_tokens, start_locals, start_ptr,
                                    ln_w, ln_b, hbuf0);

  float* hc = hbuf0;
  float* hn = hbuf1;
  for (int t = 0; t < NT; ++t) {
    emb_kernel<<<NB, 256, 0, stream>>>(hc, ln_w, ln_b, out, t);
    if (t < NT - 1) {  // final update is never observed
      gates_kernel<<<dim3(NH / BN, NB / BM), 256, 0, stream>>>(
          hc, hn, actions, act_mask, edge_tokens, w_ih, w_hh, b_ih, b_hh, t);
      float* tmp = hc; hc = hn; hn = tmp;
    }
  }
}

// Round 2
// 1401.146 us; speedup vs baseline: 3.9316x; 3.9316x over previous
//
#include <hip/hip_runtime.h>
#include <math.h>

#define NB 1024
#define NT 64
#define NH 512
#define NE 200000
#define LN_EPS 1e-5f

typedef __bf16 bf16;
typedef __attribute__((ext_vector_type(8))) __bf16 bf16x8;
typedef __attribute__((ext_vector_type(4))) float f32x4;

// ---------------- LayerNorm block statistics (256 threads, 512 elems) -------
__device__ __forceinline__ void ln_stats(float sum, float sq, float& mean, float& rstd) {
#pragma unroll
  for (int o = 32; o > 0; o >>= 1) {
    sum += __shfl_down(sum, o);
    sq  += __shfl_down(sq, o);
  }
  __shared__ float red[8];
  const int wid = threadIdx.x >> 6;
  if ((threadIdx.x & 63) == 0) { red[wid * 2] = sum; red[wid * 2 + 1] = sq; }
  __syncthreads();
  if (threadIdx.x == 0) {
    const float ts = red[0] + red[2] + red[4] + red[6];
    const float tq = red[1] + red[3] + red[5] + red[7];
    const float m  = ts * (1.0f / NH);
    const float var = tq * (1.0f / NH) - m * m;
    red[0] = m;
    red[1] = rsqrtf(var + LN_EPS);
  }
  __syncthreads();
  mean = red[0];
  rstd = red[1];
}

__device__ __forceinline__ float sigmoid_f(float x) {
  return 1.0f / (1.0f + __expf(-x));
}
__device__ __forceinline__ float tanh_f(float x) {
  x = fminf(fmaxf(x, -15.0f), 15.0f);
  const float e = __expf(2.0f * x);
  return (e - 1.0f) / (e + 1.0f);
}

// ---------------- active mask ----------------------------------------------
__global__ void active_kernel(const int* __restrict__ actions,
                              const int* __restrict__ stopidx,
                              int* __restrict__ act_mask) {
  const int b = blockIdx.x * blockDim.x + threadIdx.x;
  if (b >= NB) return;
  const int si = stopidx[b];
  bool done = false;
  for (int t = 0; t < NT; ++t) {
    const int a = actions[b * NT + t];
    const bool is_stop = (a == si) || (a < 0);
    act_mask[b * NT + t] = (!done && !is_stop) ? 1 : 0;
    done = done || is_stop;
  }
}

// ---------------- weights fp32 -> bf16 --------------------------------------
__global__ void wcvt_kernel(const float* __restrict__ wih,
                            const float* __restrict__ whh,
                            bf16* __restrict__ wihb, bf16* __restrict__ whhb) {
  const int i = (blockIdx.x * 256 + threadIdx.x) * 4;  // 786432 elems each
  const float4 a = *(const float4*)&wih[i];
  const float4 b = *(const float4*)&whh[i];
  union { bf16 h[4]; uint2 u; } pa, pb;
  pa.h[0] = (bf16)a.x; pa.h[1] = (bf16)a.y; pa.h[2] = (bf16)a.z; pa.h[3] = (bf16)a.w;
  pb.h[0] = (bf16)b.x; pb.h[1] = (bf16)b.y; pb.h[2] = (bf16)b.z; pb.h[3] = (bf16)b.w;
  *(uint2*)&wihb[i] = pa.u;
  *(uint2*)&whhb[i] = pb.u;
}

// ---------------- gather all edge rows -> bf16 X[b*NT+t][H] -----------------
__global__ void xall_kernel(const int* __restrict__ actions,
                            const float* __restrict__ edges,
                            bf16* __restrict__ xbf) {
  const int row = blockIdx.x;  // b*NT + t
  int a = actions[row];
  a = min(max(a, 0), NE - 1);
  const int i = threadIdx.x * 2;
  const float2 v = *(const float2*)&edges[(size_t)a * NH + i];
  union { bf16 h[2]; unsigned u; } p;
  p.h[0] = (bf16)v.x; p.h[1] = (bf16)v.y;
  *(unsigned*)&xbf[(size_t)row * NH + i] = p.u;
}

// ---------------- h0 = LN(question + segment_mean(node_tokens)) -------------
__global__ void h0_kernel(const float* __restrict__ q,
                          const float* __restrict__ nodes,
                          const int* __restrict__ locals,
                          const int* __restrict__ ptr,
                          const float* __restrict__ lnw,
                          const float* __restrict__ lnb,
                          float* __restrict__ h0, bf16* __restrict__ h0b) {
  const int b = blockIdx.x;
  const int i = threadIdx.x * 2;
  const int p0 = ptr[b], p1 = ptr[b + 1];
  const float denom = fmaxf((float)(p1 - p0), 1.0f);
  float s0 = 0.f, s1 = 0.f;
  for (int p = p0; p < p1; ++p) {
    const int node = locals[p];
    const float2 nv = *(const float2*)&nodes[(size_t)node * NH + i];
    s0 += nv.x; s1 += nv.y;
  }
  const float2 qv = *(const float2*)&q[(size_t)b * NH + i];
  const float v0 = qv.x + s0 / denom;
  const float v1 = qv.y + s1 / denom;
  float mean, rstd;
  ln_stats(v0 + v1, v0 * v0 + v1 * v1, mean, rstd);
  const float2 lw = *(const float2*)&lnw[i];
  const float2 lb = *(const float2*)&lnb[i];
  float2 o;
  o.x = (v0 - mean) * rstd * lw.x + lb.x;
  o.y = (v1 - mean) * rstd * lw.y + lb.y;
  *(float2*)&h0[(size_t)b * NH + i] = o;
  union { bf16 h[2]; unsigned u; } p;
  p.h[0] = (bf16)o.x; p.h[1] = (bf16)o.y;
  *(unsigned*)&h0b[(size_t)b * NH + i] = p.u;
}

// ---------------- MFMA GRU step ---------------------------------------------
// Block: 512 thr = 8 waves. Tile: 64 rows (b) x 32 cols (h). Grid (16,16)=256.
// Wave w: m-strip (w&3)*16, n-tile (w>>2) of 2. Accs: R,Z,NI,NH f32x4 each.
#define BK 128
__global__ __launch_bounds__(512) void gates_kernel(
    const float* __restrict__ hs_t, float* __restrict__ hs_n,
    const bf16* __restrict__ hbf, bf16* __restrict__ hbf_n,
    const bf16* __restrict__ xbf,
    const bf16* __restrict__ wihb, const bf16* __restrict__ whhb,
    const float* __restrict__ b_ih, const float* __restrict__ b_hh,
    const int* __restrict__ act_mask, int t) {
  __shared__ bf16 Xs[64][BK + 8];
  __shared__ bf16 Hs[64][BK + 8];
  __shared__ bf16 Wi[96][BK + 8];
  __shared__ bf16 Wh[96][BK + 8];
  __shared__ int s_any;

  const int tid = threadIdx.x;
  const int c0 = blockIdx.x * 32;
  const int b0 = blockIdx.y * 64;

  if (tid == 0) s_any = 0;
  __syncthreads();
  if (tid < 64 && act_mask[(b0 + tid) * NT + t]) s_any = 1;  // benign race
  __syncthreads();

  if (!s_any) {  // whole tile inactive: pass h through (fp32 + bf16 copies)
    const int row = tid >> 3, c4 = (tid & 7) * 4;
    const size_t off = (size_t)(b0 + row) * NH + c0 + c4;
    const float4 v = *(const float4*)&hs_t[off];
    *(float4*)&hs_n[off] = v;
    union { bf16 h[4]; uint2 u; } p;
    p.h[0] = (bf16)v.x; p.h[1] = (bf16)v.y; p.h[2] = (bf16)v.z; p.h[3] = (bf16)v.w;
    *(uint2*)&hbf_n[off] = p.u;
    return;
  }

  const int wave = tid >> 6, lane = tid & 63;
  const int ln15 = lane & 15, q8 = (lane >> 4) * 8;
  const int wrow = (wave & 3) * 16;
  const int nt = wave >> 2;

  f32x4 aR = {0, 0, 0, 0}, aZ = {0, 0, 0, 0}, aNI = {0, 0, 0, 0}, aNH = {0, 0, 0, 0};

  for (int kb = 0; kb < NH; kb += BK) {
    if (kb) __syncthreads();
#pragma unroll
    for (int i = 0; i < 2; ++i) {  // stage X,H: 64 rows x 128 k (bf16)
      const int idx = tid + 512 * i;
      const int row = idx >> 4, c8 = (idx & 15) * 8;
      *(int4*)&Hs[row][c8] = *(const int4*)&hbf[(size_t)(b0 + row) * NH + kb + c8];
      *(int4*)&Xs[row][c8] =
          *(const int4*)&xbf[((size_t)(b0 + row) * NT + t) * NH + kb + c8];
    }
#pragma unroll
    for (int i = 0; i < 3; ++i) {  // stage W: 96 rows x 128 k, both matrices
      const int idx = tid + 512 * i;
      const int row = idx >> 4, c8 = (idx & 15) * 8;
      const int g = row >> 5, n = row & 31;
      const size_t gr = ((size_t)g * NH + c0 + n) * NH + kb + c8;
      *(int4*)&Wi[row][c8] = *(const int4*)&wihb[gr];
      *(int4*)&Wh[row][c8] = *(const int4*)&whhb[gr];
    }
    __syncthreads();
#pragma unroll
    for (int k = 0; k < BK; k += 32) {
      const bf16x8 ax = *(const bf16x8*)&Xs[wrow + ln15][k + q8];
      const bf16x8 ah = *(const bf16x8*)&Hs[wrow + ln15][k + q8];
      const int wr = nt * 16 + ln15;
      const bf16x8 biR = *(const bf16x8*)&Wi[wr][k + q8];
      const bf16x8 bhR = *(const bf16x8*)&Wh[wr][k + q8];
      const bf16x8 biZ = *(const bf16x8*)&Wi[32 + wr][k + q8];
      const bf16x8 bhZ = *(const bf16x8*)&Wh[32 + wr][k + q8];
      const bf16x8 biN = *(const bf16x8*)&Wi[64 + wr][k + q8];
      const bf16x8 bhN = *(const bf16x8*)&Wh[64 + wr][k + q8];
      aR = __builtin_amdgcn_mfma_f32_16x16x32_bf16(ax, biR, aR, 0, 0, 0);
      aR = __builtin_amdgcn_mfma_f32_16x16x32_bf16(ah, bhR, aR, 0, 0, 0);
      aZ = __builtin_amdgcn_mfma_f32_16x16x32_bf16(ax, biZ, aZ, 0, 0, 0);
      aZ = __builtin_amdgcn_mfma_f32_16x16x32_bf16(ah, bhZ, aZ, 0, 0, 0);
      aNI = __builtin_amdgcn_mfma_f32_16x16x32_bf16(ax, biN, aNI, 0, 0, 0);
      aNH = __builtin_amdgcn_mfma_f32_16x16x32_bf16(ah, bhN, aNH, 0, 0, 0);
    }
  }

  // epilogue: C/D layout col=lane&15, row=(lane>>4)*4+reg
  const int c = c0 + nt * 16 + ln15;
  const float bR = b_ih[c] + b_hh[c];
  const float bZ = b_ih[NH + c] + b_hh[NH + c];
  const float bI = b_ih[2 * NH + c];
  const float bH = b_hh[2 * NH + c];
  const int mbase = b0 + wrow + (lane >> 4) * 4;
#pragma unroll
  for (int i = 0; i < 4; ++i) {
    const int m = mbase + i;
    const int act = act_mask[m * NT + t];
    const float hp = hs_t[(size_t)m * NH + c];
    const float r = sigmoid_f(aR[i] + bR);
    const float z = sigmoid_f(aZ[i] + bZ);
    const float n = tanh_f(aNI[i] + bI + r * (aNH[i] + bH));
    const float o = act ? ((1.0f - z) * n + z * hp) : hp;
    hs_n[(size_t)m * NH + c] = o;
    hbf_n[(size_t)m * NH + c] = (bf16)o;
  }
}

// ---------------- all LN emits in one pass: out[b][t] = LN(h_states[t][b]) --
__global__ void ln_all_kernel(const float* __restrict__ hs,  // [T][B][H]
                              const float* __restrict__ lnw,
                              const float* __restrict__ lnb,
                              float* __restrict__ out) {  // [B][T][H]
  const int r = blockIdx.x;  // t*NB + b
  const int t = r >> 10, b = r & (NB - 1);
  const int i = threadIdx.x * 2;
  const float2 hv = *(const float2*)&hs[(size_t)r * NH + i];
  float mean, rstd;
  ln_stats(hv.x + hv.y, hv.x * hv.x + hv.y * hv.y, mean, rstd);
  const float2 lw = *(const float2*)&lnw[i];
  const float2 lb = *(const float2*)&lnb[i];
  float2 o;
  o.x = (hv.x - mean) * rstd * lw.x + lb.x;
  o.y = (hv.y - mean) * rstd * lw.y + lb.y;
  *(float2*)&out[((size_t)b * NT + t) * NH + i] = o;
}

// ---------------- host-side launch ------------------------------------------
extern "C" void kernel_launch(void* const* d_in, const int* in_sizes, int n_in,
                              void* d_out, int out_size, void* d_ws, size_t ws_size,
                              hipStream_t stream) {
  const int*   actions      = (const int*)d_in[0];
  const float* edge_tokens  = (const float*)d_in[1];
  const int*   stop_indices = (const int*)d_in[2];
  const float* question     = (const float*)d_in[3];
  const float* node_tokens  = (const float*)d_in[4];
  const int*   start_locals = (const int*)d_in[5];
  const int*   start_ptr    = (const int*)d_in[6];
  const float* w_ih         = (const float*)d_in[7];
  const float* w_hh         = (const float*)d_in[8];
  const float* b_ih         = (const float*)d_in[9];
  const float* b_hh         = (const float*)d_in[10];
  const float* ln_w         = (const float*)d_in[11];
  const float* ln_b         = (const float*)d_in[12];
  float* out = (float*)d_out;

  // ws layout (~205 MB of ~1.5 GB)
  bf16* Wihbf = (bf16*)d_ws;
  bf16* Whhbf = Wihbf + (size_t)3 * NH * NH;
  bf16* Xbf   = Whhbf + (size_t)3 * NH * NH;
  float* hstates = (float*)(Xbf + (size_t)NB * NT * NH);
  bf16* Hb0 = (bf16*)(hstates + (size_t)NT * NB * NH);
  bf16* Hb1 = Hb0 + (size_t)NB * NH;
  int* act_mask = (int*)(Hb1 + (size_t)NB * NH);

  active_kernel<<<NB / 256, 256, 0, stream>>>(actions, stop_indices, act_mask);
  wcvt_kernel<<<(3 * NH * NH) / (256 * 4), 256, 0, stream>>>(w_ih, w_hh, Wihbf, Whhbf);
  xall_kernel<<<NB * NT, 256, 0, stream>>>(actions, edge_tokens, Xbf);
  h0_kernel<<<NB, 256, 0, stream>>>(question, node_tokens, start_locals, start_ptr,
                                    ln_w, ln_b, hstates, Hb0);

  bf16* hbc = Hb0;
  bf16* hbn = Hb1;
  for (int t = 0; t < NT - 1; ++t) {
    gates_kernel<<<dim3(NH / 32, NB / 64), 512, 0, stream>>>(
        hstates + (size_t)t * NB * NH, hstates + (size_t)(t + 1) * NB * NH,
        hbc, hbn, Xbf, Wihbf, Whhbf, b_ih, b_hh, act_mask, t);
    bf16* tmp = hbc; hbc = hbn; hbn = tmp;
  }

  ln_all_kernel<<<NB * NT, 256, 0, stream>>>(hstates, ln_w, ln_b, out);
}